// Round 1
// baseline (356.050 us; speedup 1.0000x reference)
//
#include <hip/hip_runtime.h>

// FlowNetC correlation: out[b, (dy+4)*9+(dx+4), y, x] =
//   (1/256) * sum_c in1[b,c,y,x] * in2[b,c,y+dy,x+dx], zero-padded.
// B=8, C=256, H=96, W=128, MD=4 -> 81 displacement channels.

#define B_ 8
#define C_ 256
#define H_ 96
#define W_ 128
#define HW_ (H_ * W_) // 12288

__global__ __launch_bounds__(256) void corr_kernel(
    const float* __restrict__ in1,
    const float* __restrict__ in2,
    float* __restrict__ out)
{
    // thread -> (b, y, dy, xg); xg = group of 4 consecutive x pixels
    int tid = blockIdx.x * 256 + threadIdx.x;
    int xg  = tid & 31;          // 0..31  (32 groups * 4 px = 128 = W)
    int t   = tid >> 5;
    int dy  = t % 9;             // 0..8  -> displacement row dy-4
    t       = t / 9;
    int y   = t % H_;
    int b   = t / H_;

    int x0 = xg << 2;            // first pixel of this group
    int ry = y + dy - 4;         // source row in in2

    float acc[36];               // acc[j*4+i]: pixel x0+i, dx = j-4
    #pragma unroll
    for (int k = 0; k < 36; ++k) acc[k] = 0.f;

    bool rowok = (ry >= 0) && (ry < H_);
    if (rowok) {
        const float* p1 = in1 + (size_t)b * C_ * HW_ + (size_t)y  * W_ + x0;
        const float* p2 = in2 + (size_t)b * C_ * HW_ + (size_t)ry * W_ + (x0 - 4);
        const bool lok = (xg > 0);   // cols x0-4..x0-1 valid?
        const bool rok = (xg < 31);  // cols x0+4..x0+7 valid?

        #pragma unroll 2
        for (int c = 0; c < C_; ++c) {
            float4 a  = *(const float4*)(p1);
            float4 w1 = *(const float4*)(p2 + 4);   // cols x0..x0+3 (always valid)
            float4 w0 = make_float4(0.f, 0.f, 0.f, 0.f);
            if (lok) w0 = *(const float4*)(p2);     // cols x0-4..x0-1
            float4 w2 = make_float4(0.f, 0.f, 0.f, 0.f);
            if (rok) w2 = *(const float4*)(p2 + 8); // cols x0+4..x0+7

            float w[12] = { w0.x, w0.y, w0.z, w0.w,
                            w1.x, w1.y, w1.z, w1.w,
                            w2.x, w2.y, w2.z, w2.w };
            float av[4] = { a.x, a.y, a.z, a.w };

            #pragma unroll
            for (int j = 0; j < 9; ++j) {
                #pragma unroll
                for (int i = 0; i < 4; ++i) {
                    // col = x0 - 4 + (i + j) ; dx = j - 4
                    acc[j * 4 + i] += av[i] * w[i + j];
                }
            }
            p1 += HW_;
            p2 += HW_;
        }
    }

    const float scale = 1.f / (float)C_;
    float* po = out + (((size_t)b * 81 + (size_t)dy * 9) * H_ + y) * W_ + x0;
    #pragma unroll
    for (int j = 0; j < 9; ++j) {
        float4 o = make_float4(acc[j * 4 + 0] * scale,
                               acc[j * 4 + 1] * scale,
                               acc[j * 4 + 2] * scale,
                               acc[j * 4 + 3] * scale);
        *(float4*)po = o;   // contiguous x, aligned (x0 multiple of 4)
        po += HW_;          // next displacement channel
    }
}

extern "C" void kernel_launch(void* const* d_in, const int* in_sizes, int n_in,
                              void* d_out, int out_size, void* d_ws, size_t ws_size,
                              hipStream_t stream) {
    const float* in1 = (const float*)d_in[0];
    const float* in2 = (const float*)d_in[1];
    float* out = (float*)d_out;

    // threads = B*H*9*32 = 221184 -> 864 blocks of 256
    const int total = B_ * H_ * 9 * 32;
    corr_kernel<<<total / 256, 256, 0, stream>>>(in1, in2, out);
}